// Round 3
// baseline (1094.362 us; speedup 1.0000x reference)
//
#include <hip/hip_runtime.h>
#include <math.h>

typedef unsigned short bfu;   // raw bf16 bits (internal format)
typedef __attribute__((ext_vector_type(8))) short short8;
typedef __attribute__((ext_vector_type(4))) float floatx4;

__device__ __forceinline__ float bu2f(bfu u){
  return __builtin_bit_cast(float, (unsigned)u << 16);
}
__device__ __forceinline__ bfu f2bu(float f){
  unsigned x = __builtin_bit_cast(unsigned, f);
  unsigned r = (x + 0x7FFFu + ((x >> 16) & 1u)) >> 16;   // RNE, finite inputs
  return (bfu)r;
}

// ---------------- fp32 -> bf16 weight conversion ----------------
__global__ __launch_bounds__(256) void f2b_kernel(
    const float* __restrict__ s, bfu* __restrict__ d, int n)
{
  int i = blockIdx.x*256 + threadIdx.x;
  if (i < n) d[i] = f2bu(s[i]);
}

// ---------------- block reduce ----------------
__device__ __forceinline__ void blockReduce2(float& s, float& ss, float* sh){
#pragma unroll
  for (int off = 1; off < 64; off <<= 1){
    s  += __shfl_xor(s,  off, 64);
    ss += __shfl_xor(ss, off, 64);
  }
  int w = threadIdx.x >> 6;
  if ((threadIdx.x & 63) == 0){ sh[w] = s; sh[8 + w] = ss; }
  __syncthreads();
  s  = sh[0] + sh[1] + sh[2] + sh[3];
  ss = sh[8] + sh[9] + sh[10] + sh[11];
  __syncthreads();
}

// ---------------- channel LayerNorm of fp32 input -> bf16 out; grid (T,B), block 256 ----------------
__global__ __launch_bounds__(256) void cln_kernel(
    const float* __restrict__ X, bfu* __restrict__ OUT,
    const float* __restrict__ w, const float* __restrict__ bb, int T)
{
  __shared__ float sh[16];
  int t = blockIdx.x, b = blockIdx.y, tid = threadIdx.x;
  const float* xp = X + (size_t)b*512*T + t;
  float v0 = xp[(size_t)tid*T];
  float v1 = xp[(size_t)(tid+256)*T];
  float s = v0+v1, ss = v0*v0+v1*v1;
  blockReduce2(s, ss, sh);
  float mu = s*(1.f/512.f);
  float var = ss*(1.f/512.f) - mu*mu;
  float rs = rsqrtf(var + 1e-5f);
  bfu* op = OUT + (size_t)b*512*T + t;
  op[(size_t)tid*T]       = f2bu((v0-mu)*rs*w[tid]     + bb[tid]);
  op[(size_t)(tid+256)*T] = f2bu((v1-mu)*rs*w[tid+256] + bb[tid+256]);
}

// ---------------- phi = relu(mean_t(out_cln)*gfc_w + gfc_b); grid (512,B), block 64 ----------------
__global__ __launch_bounds__(64) void phi_kernel(
    const bfu* __restrict__ out_cln, const float* __restrict__ gw,
    const float* __restrict__ gb, float* __restrict__ phi, int T)
{
  int c = blockIdx.x, b = blockIdx.y, tid = threadIdx.x;
  const bfu* p = out_cln + ((size_t)b*512 + c)*T;
  float s = 0.f;
  for (int t = tid; t < T; t += 64) s += bu2f(p[t]);
#pragma unroll
  for (int off = 1; off < 64; off <<= 1) s += __shfl_xor(s, off, 64);
  if (tid == 0){
    float m = s / (float)T;
    phi[b*512 + c] = fmaxf(m*gw[c] + gb[c], 0.f);
  }
}

// ---------------- xatt=(cw+ckw)*psi ; y=(out*fc_w+fc_b)*phi ----------------
__global__ __launch_bounds__(256) void prep_kernel(
    const bfu* __restrict__ out_cln, const float* __restrict__ phi,
    const float* __restrict__ psi_w, const float* __restrict__ psi_b,
    const float* __restrict__ cw_w, const float* __restrict__ cw_b,
    const float* __restrict__ ckw_w, const float* __restrict__ ckw_b, int ckw_k,
    const float* __restrict__ fc_w, const float* __restrict__ fc_b,
    bfu* __restrict__ xatt, bfu* __restrict__ y, int T)
{
  int idx = blockIdx.x*256 + threadIdx.x;
  if (idx >= 2*512*T) return;
  int t = idx % T, c = (idx / T) & 511, b = idx / (512*T);
  const bfu* xp = out_cln + ((size_t)b*512 + c)*T;
  float win[5];
#pragma unroll
  for (int j = 0; j < 5; j++){
    int tt = t + j - 2;
    win[j] = (tt >= 0 && tt < T) ? bu2f(xp[tt]) : 0.f;
  }
  float x0 = win[2];
  float psi = psi_b[c];
  float cw  = cw_b[c];
#pragma unroll
  for (int j = 0; j < 3; j++){
    psi += win[1+j]*psi_w[c*3+j];
    cw  += win[1+j]*cw_w[c*3+j];
  }
  float ckw = ckw_b[c];
  if (ckw_k == 1)      ckw += win[2]*ckw_w[c];
  else if (ckw_k == 3){
#pragma unroll
    for (int j = 0; j < 3; j++) ckw += win[1+j]*ckw_w[c*3+j];
  } else {
#pragma unroll
    for (int j = 0; j < 5; j++) ckw += win[j]*ckw_w[c*5+j];
  }
  xatt[idx] = f2bu((cw + ckw)*psi);
  y[idx]    = f2bu((x0*fc_w[c] + fc_b[c]) * phi[b*512 + c]);
}

// ---------------- q/k/v depthwise k=3 convs (no bias) ----------------
__global__ __launch_bounds__(256) void qkvpre_kernel(
    const bfu* __restrict__ xatt, const bfu* __restrict__ y,
    const float* __restrict__ dw,   // (3,C,3) fp32
    bfu* __restrict__ qpre, bfu* __restrict__ kpre, bfu* __restrict__ vpre, int T)
{
  int idx = blockIdx.x*256 + threadIdx.x;
  if (idx >= 2*512*T) return;
  int t = idx % T, c = (idx / T) & 511;
  size_t rowbase = (size_t)(idx - t);
  const bfu* xa = xatt + rowbase;
  const bfu* yy = y + rowbase;
  float wx[3], wy[3];
#pragma unroll
  for (int j = 0; j < 3; j++){
    int tt = t + j - 1;
    bool ok = (tt >= 0 && tt < T);
    wx[j] = ok ? bu2f(xa[tt]) : 0.f;
    wy[j] = ok ? bu2f(yy[tt]) : 0.f;
  }
  float q = 0.f, k = 0.f, v = 0.f;
#pragma unroll
  for (int j = 0; j < 3; j++){
    q += wx[j]*dw[0*512*3 + c*3 + j];
    k += wy[j]*dw[1*512*3 + c*3 + j];
    v += wy[j]*dw[2*512*3 + c*3 + j];
  }
  qpre[idx] = f2bu(q); kpre[idx] = f2bu(k); vpre[idx] = f2bu(v);
}

// ---------------- cLN of q/k/v in-place ----------------
__global__ __launch_bounds__(256) void cln3_kernel(
    bfu* __restrict__ Q, bfu* __restrict__ K, bfu* __restrict__ V,
    const float* __restrict__ nw, const float* __restrict__ nb, int T)
{
  __shared__ float sh[16];
  int t = blockIdx.x, b = blockIdx.y, tid = threadIdx.x;
  size_t base = (size_t)b*512*T + t;
  bfu* ptrs[3] = {Q + base, K + base, V + base};
#pragma unroll
  for (int j = 0; j < 3; j++){
    bfu* p = ptrs[j];
    float v0 = bu2f(p[(size_t)tid*T]);
    float v1 = bu2f(p[(size_t)(tid+256)*T]);
    float s = v0+v1, ss = v0*v0+v1*v1;
    blockReduce2(s, ss, sh);
    float mu = s*(1.f/512.f);
    float var = ss*(1.f/512.f) - mu*mu;
    float rs = rsqrtf(var + 1e-5f);
    p[(size_t)tid*T]       = f2bu((v0-mu)*rs*nw[j*512+tid]     + nb[j*512+tid]);
    p[(size_t)(tid+256)*T] = f2bu((v1-mu)*rs*nw[j*512+tid+256] + nb[j*512+tid+256]);
  }
}

// ---------------- GEMM: OUT[b,m,n] = sum_k W[m,k]*X[b,k,n] + bias[m] (+res) (gelu?) ----------------
// MFMA 16x16x32 bf16; C/D: row(m)=quad*4+reg, col(n)=lane&15 (m89/m91-verified)
#define LDA 40
__global__ __launch_bounds__(256) void gemm_kernel(
    const bfu* __restrict__ W, const bfu* __restrict__ X,
    const float* __restrict__ bias,
    bfu* __restrict__ OUT, float* __restrict__ OUTF,
    const bfu* __restrict__ res_bf, const float* __restrict__ res_f,
    int M, int N, int K, int gelu)
{
  __shared__ __align__(16) short As[64*LDA];
  __shared__ __align__(16) short Bs[64*LDA];
  int b = blockIdx.z;
  int n0 = blockIdx.x*64, m0 = blockIdx.y*64;
  const bfu* Xb = X + (size_t)b*K*N;
  int tid = threadIdx.x, lane = tid & 63, w = tid >> 6;
  int quad = lane >> 4, l16 = lane & 15;
  int wm = (w >> 1)*32, wn = (w & 1)*32;

  floatx4 acc[2][2];
#pragma unroll
  for (int i = 0; i < 2; i++)
#pragma unroll
    for (int j = 0; j < 2; j++) acc[i][j] = (floatx4){0.f,0.f,0.f,0.f};

  int ar = tid >> 2, ac = (tid & 3)*8;
  int bn = tid & 63, bk = tid >> 6;

  for (int k0 = 0; k0 < K; k0 += 32){
    __syncthreads();
    *(short8*)&As[ar*LDA + ac] = *(const short8*)&W[(size_t)(m0+ar)*K + k0 + ac];
#pragma unroll
    for (int kk = 0; kk < 8; kk++){
      int kr = kk*4 + bk;
      Bs[bn*LDA + kr] = (short)Xb[(size_t)(k0+kr)*N + n0 + bn];
    }
    __syncthreads();
    short8 af0 = *(short8*)&As[(wm + l16)*LDA + quad*8];
    short8 af1 = *(short8*)&As[(wm + 16 + l16)*LDA + quad*8];
    short8 bf0 = *(short8*)&Bs[(wn + l16)*LDA + quad*8];
    short8 bf1 = *(short8*)&Bs[(wn + 16 + l16)*LDA + quad*8];
    acc[0][0] = __builtin_amdgcn_mfma_f32_16x16x32_bf16(af0, bf0, acc[0][0], 0,0,0);
    acc[0][1] = __builtin_amdgcn_mfma_f32_16x16x32_bf16(af0, bf1, acc[0][1], 0,0,0);
    acc[1][0] = __builtin_amdgcn_mfma_f32_16x16x32_bf16(af1, bf0, acc[1][0], 0,0,0);
    acc[1][1] = __builtin_amdgcn_mfma_f32_16x16x32_bf16(af1, bf1, acc[1][1], 0,0,0);
  }

  size_t obase = (size_t)b*M*N;
#pragma unroll
  for (int mi = 0; mi < 2; mi++){
#pragma unroll
    for (int ni = 0; ni < 2; ni++){
#pragma unroll
      for (int i = 0; i < 4; i++){
        int m = m0 + wm + mi*16 + quad*4 + i;
        int n = n0 + wn + ni*16 + l16;
        size_t o = obase + (size_t)m*N + n;
        float v = acc[mi][ni][i] + bias[m];
        if (res_bf) v += bu2f(res_bf[o]);
        if (res_f)  v += res_f[o];
        if (gelu) v = 0.5f*v*(1.f + erff(v*0.70710678f));
        if (OUTF) OUTF[o] = v;
        else      OUT[o]  = f2bu(v);
      }
    }
  }
}

// ---------------- flash attention: Q,K,V,O in (B, H*64, T); grid (T/64, B*8), block 256 ----------------
__global__ __launch_bounds__(256) void attn_kernel(
    const bfu* __restrict__ Q, const bfu* __restrict__ Kt,
    const bfu* __restrict__ V, bfu* __restrict__ O, int T)
{
  __shared__ __align__(16) short Qs[64*72];
  __shared__ __align__(16) short Ks[64*72];
  __shared__ __align__(16) short Ps[4][16*72];
  int bh = blockIdx.y;
  int b = bh >> 3, h = bh & 7;
  size_t base = ((size_t)b*512 + h*64)*T;
  const bfu* Qp = Q + base;
  const bfu* Kp = Kt + base;
  const bfu* Vp = V + base;
  bfu* Op = O + base;
  int t0 = blockIdx.x*64;
  int tid = threadIdx.x, lane = tid & 63, w = tid >> 6;
  int quad = lane >> 4, l16 = lane & 15;
  int qw = w*16;

  // stage Q (scaled by 1/sqrt(64)) into LDS [q][d]
  for (int idx = tid; idx < 512; idx += 256){
    int d = idx >> 3, qg = (idx & 7)*8;
    short8 qv = *(const short8*)&Qp[(size_t)d*T + t0 + qg];
#pragma unroll
    for (int j = 0; j < 8; j++)
      Qs[(qg+j)*72 + d] = (short)f2bu(bu2f((bfu)qv[j]) * 0.125f);
  }

  floatx4 o[4];
#pragma unroll
  for (int i = 0; i < 4; i++) o[i] = (floatx4){0.f,0.f,0.f,0.f};
  float mcur[4], lcur[4];
#pragma unroll
  for (int i = 0; i < 4; i++){ mcur[i] = -INFINITY; lcur[i] = 0.f; }

  for (int s0 = 0; s0 < T; s0 += 64){
    __syncthreads();
    for (int idx = tid; idx < 512; idx += 256){
      int d = idx >> 3, sg = (idx & 7)*8;
      short8 kv = *(const short8*)&Kp[(size_t)d*T + s0 + sg];
#pragma unroll
      for (int j = 0; j < 8; j++) Ks[(sg+j)*72 + d] = kv[j];
    }
    __syncthreads();

    short8 a0 = *(short8*)&Qs[(qw + l16)*72 + quad*8];
    short8 a1 = *(short8*)&Qs[(qw + l16)*72 + 32 + quad*8];
    floatx4 sf[4];
#pragma unroll
    for (int sn = 0; sn < 4; sn++){
      short8 b0 = *(short8*)&Ks[(sn*16 + l16)*72 + quad*8];
      short8 b1 = *(short8*)&Ks[(sn*16 + l16)*72 + 32 + quad*8];
      floatx4 acc = (floatx4){0.f,0.f,0.f,0.f};
      acc = __builtin_amdgcn_mfma_f32_16x16x32_bf16(a0, b0, acc, 0,0,0);
      acc = __builtin_amdgcn_mfma_f32_16x16x32_bf16(a1, b1, acc, 0,0,0);
      sf[sn] = acc;
    }

    // online softmax; row r = quad*4+i (q), col = sn*16+l16 (s)
    float alpha[4];
#pragma unroll
    for (int i = 0; i < 4; i++){
      float lm = fmaxf(fmaxf(sf[0][i], sf[1][i]), fmaxf(sf[2][i], sf[3][i]));
#pragma unroll
      for (int off = 1; off < 16; off <<= 1) lm = fmaxf(lm, __shfl_xor(lm, off, 16));
      float mnew = fmaxf(mcur[i], lm);
      alpha[i] = __expf(mcur[i] - mnew);
      float rs = 0.f;
#pragma unroll
      for (int sn = 0; sn < 4; sn++){
        float p = __expf(sf[sn][i] - mnew);
        sf[sn][i] = p;
        rs += p;
      }
#pragma unroll
      for (int off = 1; off < 16; off <<= 1) rs += __shfl_xor(rs, off, 16);
      lcur[i] = lcur[i]*alpha[i] + rs;
      mcur[i] = mnew;
    }

    // P: C-layout -> LDS -> A-layout (per-wave buffer; barrier is cheap insurance)
#pragma unroll
    for (int i = 0; i < 4; i++)
#pragma unroll
      for (int sn = 0; sn < 4; sn++)
        Ps[w][(quad*4 + i)*72 + sn*16 + l16] = (short)f2bu(sf[sn][i]);
    __syncthreads();

#pragma unroll
    for (int dn = 0; dn < 4; dn++)
#pragma unroll
      for (int i = 0; i < 4; i++) o[dn][i] *= alpha[i];

    short8 pa0 = *(short8*)&Ps[w][l16*72 + quad*8];
    short8 pa1 = *(short8*)&Ps[w][l16*72 + 32 + quad*8];
#pragma unroll
    for (int dn = 0; dn < 4; dn++){
      const bfu* vrow = Vp + (size_t)(dn*16 + l16)*T + s0;
      short8 v0 = *(const short8*)&vrow[quad*8];
      short8 v1 = *(const short8*)&vrow[32 + quad*8];
      o[dn] = __builtin_amdgcn_mfma_f32_16x16x32_bf16(pa0, v0, o[dn], 0,0,0);
      o[dn] = __builtin_amdgcn_mfma_f32_16x16x32_bf16(pa1, v1, o[dn], 0,0,0);
    }
  }

#pragma unroll
  for (int dn = 0; dn < 4; dn++)
#pragma unroll
    for (int i = 0; i < 4; i++)
      Op[(size_t)(dn*16 + l16)*T + t0 + qw + quad*4 + i] = f2bu(o[dn][i] / lcur[i]);
}

// ---------------- GroupNorm (16 groups of 32 channels) ----------------
__global__ __launch_bounds__(256) void gnstats_kernel(
    const bfu* __restrict__ X, float* __restrict__ st, int T)
{
  __shared__ float sh[16];
  int g = blockIdx.x, b = blockIdx.y, tid = threadIdx.x;
  const bfu* p = X + ((size_t)b*512 + g*32)*T;
  int n = 32*T;
  float s = 0.f, ss = 0.f;
  for (int i = tid; i < n; i += 256){
    float v = bu2f(p[i]); s += v; ss += v*v;
  }
  blockReduce2(s, ss, sh);
  if (tid == 0){
    float mu = s / (float)n;
    float var = ss / (float)n - mu*mu;
    st[(b*16 + g)*2]     = mu;
    st[(b*16 + g)*2 + 1] = rsqrtf(var + 1e-5f);
  }
}

__global__ __launch_bounds__(256) void gnapply_kernel(
    const bfu* __restrict__ X, const float* __restrict__ st,
    const float* __restrict__ w, const float* __restrict__ bb,
    bfu* __restrict__ OUT, int T)
{
  int idx = blockIdx.x*256 + threadIdx.x;
  if (idx >= 2*512*T) return;
  int c = (idx / T) & 511, b = idx / (512*T);
  int g = c >> 5;
  float mu = st[(b*16 + g)*2], rs = st[(b*16 + g)*2 + 1];
  OUT[idx] = f2bu((bu2f(X[idx]) - mu)*rs*w[c] + bb[c]);
}

// ---------------- launch ----------------
extern "C" void kernel_launch(void* const* d_in, const int* in_sizes, int n_in,
                              void* d_out, int out_size, void* d_ws, size_t ws_size,
                              hipStream_t stream)
{
  (void)in_sizes; (void)n_in; (void)out_size; (void)ws_size;
  const int B = 2;
  const float* xs_in[3] = {(const float*)d_in[0], (const float*)d_in[1], (const float*)d_in[2]};
  const int Ts[3] = {512, 1024, 2048};
  const float* ln_w   = (const float*)d_in[6];
  const float* ln_b   = (const float*)d_in[7];
  const float* gn_w   = (const float*)d_in[8];
  const float* gn_b   = (const float*)d_in[9];
  const float* psi_w  = (const float*)d_in[10];
  const float* psi_b  = (const float*)d_in[11];
  const float* fc_w   = (const float*)d_in[12];
  const float* fc_b   = (const float*)d_in[13];
  const float* convw_w = (const float*)d_in[14];
  const float* convw_b = (const float*)d_in[15];
  const float* ckw_ws[3] = {(const float*)d_in[16], (const float*)d_in[18], (const float*)d_in[20]};
  const float* ckw_bs[3] = {(const float*)d_in[17], (const float*)d_in[19], (const float*)d_in[21]};
  const int   ckw_ks[3] = {1, 3, 5};
  const float* gfc_w  = (const float*)d_in[22];
  const float* gfc_b  = (const float*)d_in[23];
  const float* ca_dw  = (const float*)d_in[24];
  const float* ca_nw  = (const float*)d_in[25];
  const float* ca_nb  = (const float*)d_in[26];
  const float* qkv_w  = (const float*)d_in[27];
  const float* qkv_b  = (const float*)d_in[28];
  const float* proj_w = (const float*)d_in[29];
  const float* proj_b = (const float*)d_in[30];
  const float* mlp1_w = (const float*)d_in[31];
  const float* mlp1_b = (const float*)d_in[32];
  const float* mlp2_w = (const float*)d_in[33];
  const float* mlp2_b = (const float*)d_in[34];

  char* ws = (char*)d_ws;
  const size_t P = (size_t)2*512*2048*2;   // one (B,C,Tmax) bf16 plane = 4 MB
  bfu* out_cln = (bfu*)(ws + 0*P);                  // cln .. proj-res
  bfu* xatt    = (bfu*)(ws + 1*P);                  // prep .. qkvpre
  bfu* ybuf    = (bfu*)(ws + 2*P);                  // prep .. qkvpre
  bfu* qpre    = (bfu*)(ws + 3*P);                  // qkvpre .. gemmQ
  bfu* kpre    = (bfu*)(ws + 4*P);                  // qkvpre .. gemmK
  bfu* vpre    = (bfu*)(ws + 5*P);                  // qkvpre .. gemmV
  bfu* qbuf    = (bfu*)(ws + 1*P);                  // gemmQ .. attn
  bfu* kbuf    = (bfu*)(ws + 2*P);                  // gemmK .. attn
  bfu* vbuf    = (bfu*)(ws + 3*P);                  // gemmV .. attn
  bfu* attout  = (bfu*)(ws + 4*P);                  // attn .. proj
  bfu* resb    = (bfu*)(ws + 6*P);                  // proj .. mlp2-res
  bfu* gnout   = (bfu*)(ws + 1*P);                  // gnapply .. mlp1
  bfu* hidden  = (bfu*)(ws + 2*P);                  // mlp1 .. mlp2 (planes 2..5)
  float* phi   = (float*)(ws + 7*P);
  float* gnst  = (float*)(ws + 7*P + 8192);
  // bf16 copies of GEMM weights (converted every call; graph-safe)
  bfu* wqkvB = (bfu*)(ws + 7*P + 65536);            // 3*512*512
  bfu* wprojB = wqkvB + 3*512*512;                  // 512*512
  bfu* wm1B   = wprojB + 512*512;                   // 2048*512
  bfu* wm2B   = wm1B + 2048*512;                    // 512*2048

  f2b_kernel<<<(3*512*512+255)/256, 256, 0, stream>>>(qkv_w,  wqkvB, 3*512*512);
  f2b_kernel<<<(512*512+255)/256,   256, 0, stream>>>(proj_w, wprojB, 512*512);
  f2b_kernel<<<(2048*512+255)/256,  256, 0, stream>>>(mlp1_w, wm1B, 2048*512);
  f2b_kernel<<<(2048*512+255)/256,  256, 0, stream>>>(mlp2_w, wm2B, 512*2048);

  size_t out_off = 0;
  for (int bi = 0; bi < 3; bi++){
    int T = Ts[bi];
    const float* x = xs_in[bi];
    float* outp = (float*)d_out + out_off;
    int nelem = B*512*T;
    dim3 eb((nelem + 255)/256);

    cln_kernel<<<dim3(T, B), 256, 0, stream>>>(x, out_cln, ln_w, ln_b, T);
    phi_kernel<<<dim3(512, B), 64, 0, stream>>>(out_cln, gfc_w, gfc_b, phi, T);
    prep_kernel<<<eb, 256, 0, stream>>>(out_cln, phi, psi_w, psi_b,
        convw_w + bi*512*3, convw_b + bi*512, ckw_ws[bi], ckw_bs[bi], ckw_ks[bi],
        fc_w, fc_b, xatt, ybuf, T);
    qkvpre_kernel<<<eb, 256, 0, stream>>>(xatt, ybuf, ca_dw, qpre, kpre, vpre, T);
    cln3_kernel<<<dim3(T, B), 256, 0, stream>>>(qpre, kpre, vpre, ca_nw, ca_nb, T);
    gemm_kernel<<<dim3(T/64, 8, B), 256, 0, stream>>>(wqkvB + 0*512*512, qpre, qkv_b + 0*512, qbuf, nullptr, nullptr, nullptr, 512, T, 512, 0);
    gemm_kernel<<<dim3(T/64, 8, B), 256, 0, stream>>>(wqkvB + 1*512*512, kpre, qkv_b + 1*512, kbuf, nullptr, nullptr, nullptr, 512, T, 512, 0);
    gemm_kernel<<<dim3(T/64, 8, B), 256, 0, stream>>>(wqkvB + 2*512*512, vpre, qkv_b + 2*512, vbuf, nullptr, nullptr, nullptr, 512, T, 512, 0);
    attn_kernel<<<dim3(T/64, B*8), 256, 0, stream>>>(qbuf, kbuf, vbuf, attout, T);
    gemm_kernel<<<dim3(T/64, 8, B), 256, 0, stream>>>(wprojB, attout, proj_b, resb, nullptr, out_cln, x, 512, T, 512, 0);
    gnstats_kernel<<<dim3(16, B), 256, 0, stream>>>(resb, gnst, T);
    gnapply_kernel<<<eb, 256, 0, stream>>>(resb, gnst, gn_w, gn_b, gnout, T);
    gemm_kernel<<<dim3(T/64, 32, B), 256, 0, stream>>>(wm1B, gnout, mlp1_b, hidden, nullptr, nullptr, nullptr, 2048, T, 512, 1);
    gemm_kernel<<<dim3(T/64, 8, B), 256, 0, stream>>>(wm2B, hidden, mlp2_b, nullptr, outp, resb, nullptr, 512, T, 2048, 0);

    out_off += (size_t)nelem;
  }
}